// Round 4
// baseline (651.916 us; speedup 1.0000x reference)
//
#include <hip/hip_runtime.h>

typedef unsigned short u16;
typedef unsigned int   u32;
typedef __bf16 bf16x8 __attribute__((ext_vector_type(8)));
typedef float  f32x4  __attribute__((ext_vector_type(4)));

#define DEVI __device__ __forceinline__

// B=8, S=N=1024, IMG_DIM=1024, TXT_DIM=768, INNER=1024, N_HEADS=16, HEAD_DIM=64, P=3
// Inputs: FLOAT32 (reference dtype). Outputs: FLOAT32 (reference dtype).
// out layout: Q | K | V | Q' | K', each [B,16,L,64] flat = 8*16*1024*64 elements

DEVI u16 f2bf(float f) {
    u32 u = __float_as_uint(f);
    return (u16)((u + 0x7fffu + ((u >> 16) & 1u)) >> 16);   // RNE fp32->bf16
}
DEVI u32 pk2(float lo, float hi) { return (u32)f2bf(lo) | ((u32)f2bf(hi) << 16); }

// ---------------------------------------------------------------------------
// Routing: per token, scores[p] = dot(x, Wr[p]) in fp32; first argmax (strict >,
// matching np.argmax); compact token indices into per-bank lists via atomics.
// ---------------------------------------------------------------------------
__global__ void route_kernel(const float* __restrict__ X, const float* __restrict__ Wr,
                             int D, int ntok, int* __restrict__ cnt, int* __restrict__ list)
{
    int tok = blockIdx.x * blockDim.x + threadIdx.x;
    if (tok >= ntok) return;
    const float* x  = X + (size_t)tok * D;
    const float* w0 = Wr;
    const float* w1 = Wr + D;
    const float* w2 = Wr + 2 * D;
    float a0 = 0.f, a1 = 0.f, a2 = 0.f;
    for (int d = 0; d < D; d += 4) {
        float4 xv = *(const float4*)(x + d);
        float4 v0 = *(const float4*)(w0 + d);
        float4 v1 = *(const float4*)(w1 + d);
        float4 v2 = *(const float4*)(w2 + d);
        a0 += xv.x * v0.x + xv.y * v0.y + xv.z * v0.z + xv.w * v0.w;
        a1 += xv.x * v1.x + xv.y * v1.y + xv.z * v1.z + xv.w * v1.w;
        a2 += xv.x * v2.x + xv.y * v2.y + xv.z * v2.z + xv.w * v2.w;
    }
    int s = 0; float best = a0;
    if (a1 > best) { best = a1; s = 1; }
    if (a2 > best) { best = a2; s = 2; }
    int slot = atomicAdd(&cnt[s], 1);
    list[s * 8192 + slot] = tok;
}

// ---------------------------------------------------------------------------
// GEMM core: 128x128 tile, BK=32, 4 waves in 2x2, each wave 4x4 MFMA tiles of
// 16x16x32 bf16 (fp32 accumulate). Inputs are fp32 in global memory; staging
// converts fp32 -> bf16 (RNE) on the fly via VGPR round-trip.
// Thread tid stages 8-elem chunks c=tid and c=tid+256 of each 128x32 tile:
// chunk c -> LDS u16 offset 8*c (row c>>2, k-off (c&3)*8). Every LDS byte is
// written before any read; barriers on both sides.
// ---------------------------------------------------------------------------
template <int KD>
DEVI void gemm_core(const float* gA1, const float* gA2, const float* gB1, const float* gB2,
                    u16* As, u16* Bs, int tid, int wv, int lane, f32x4 (&acc)[4][4])
{
    uint4* sA1 = (uint4*)(As + 8 * tid);
    uint4* sA2 = (uint4*)(As + 8 * (tid + 256));
    uint4* sB1 = (uint4*)(Bs + 8 * tid);
    uint4* sB2 = (uint4*)(Bs + 8 * (tid + 256));
    const int row15 = lane & 15;
    const int quad  = lane >> 4;
    const int wm = (wv & 1) * 64;
    const int wn = (wv >> 1) * 64;

    for (int k0 = 0; k0 < KD; k0 += 32) {
        float4 a1l = *(const float4*)(gA1 + k0);
        float4 a1h = *(const float4*)(gA1 + k0 + 4);
        float4 a2l = *(const float4*)(gA2 + k0);
        float4 a2h = *(const float4*)(gA2 + k0 + 4);
        float4 b1l = *(const float4*)(gB1 + k0);
        float4 b1h = *(const float4*)(gB1 + k0 + 4);
        float4 b2l = *(const float4*)(gB2 + k0);
        float4 b2h = *(const float4*)(gB2 + k0 + 4);
        uint4 pa1 = { pk2(a1l.x, a1l.y), pk2(a1l.z, a1l.w), pk2(a1h.x, a1h.y), pk2(a1h.z, a1h.w) };
        uint4 pa2 = { pk2(a2l.x, a2l.y), pk2(a2l.z, a2l.w), pk2(a2h.x, a2h.y), pk2(a2h.z, a2h.w) };
        uint4 pb1 = { pk2(b1l.x, b1l.y), pk2(b1l.z, b1l.w), pk2(b1h.x, b1h.y), pk2(b1h.z, b1h.w) };
        uint4 pb2 = { pk2(b2l.x, b2l.y), pk2(b2l.z, b2l.w), pk2(b2h.x, b2h.y), pk2(b2h.z, b2h.w) };
        *sA1 = pa1;
        *sA2 = pa2;
        *sB1 = pb1;
        *sB2 = pb2;
        __syncthreads();

        bf16x8 a[4], b[4];
#pragma unroll
        for (int i = 0; i < 4; ++i)
            a[i] = *(const bf16x8*)(As + (wm + i * 16 + row15) * 32 + quad * 8);
#pragma unroll
        for (int j = 0; j < 4; ++j)
            b[j] = *(const bf16x8*)(Bs + (wn + j * 16 + row15) * 32 + quad * 8);
#pragma unroll
        for (int i = 0; i < 4; ++i)
#pragma unroll
            for (int j = 0; j < 4; ++j)
                acc[i][j] = __builtin_amdgcn_mfma_f32_16x16x32_bf16(a[i], b[j], acc[i][j], 0, 0, 0);
        __syncthreads();
    }
}

// ---------------------------------------------------------------------------
// Plain GEMM: C[m,n] = sum_k A[m,k] * W[n,k], written to head layout (fp32).
// m = b*1024 + l ; n = h*64 + d ; out[((b*16+h)*1024 + l)*64 + d]
// ---------------------------------------------------------------------------
template <int KD>
__global__ __launch_bounds__(256)
void gemm_heads(const float* __restrict__ A, const float* __restrict__ W, float* __restrict__ out)
{
    __shared__ __align__(16) u16 As[128 * 32];
    __shared__ __align__(16) u16 Bs[128 * 32];
    const int tid  = threadIdx.x;
    const int lane = tid & 63;
    const int wv   = tid >> 6;
    const int rowbase = blockIdx.x * 128;
    const int nbase   = blockIdx.y * 128;
    const int r1   = tid >> 2;
    const int koff = (tid & 3) * 8;

    const float* gA1 = A + (size_t)(rowbase + r1) * KD + koff;
    const float* gA2 = A + (size_t)(rowbase + 64 + r1) * KD + koff;
    const float* gB1 = W + (size_t)(nbase + r1) * KD + koff;
    const float* gB2 = W + (size_t)(nbase + 64 + r1) * KD + koff;

    f32x4 acc[4][4];
#pragma unroll
    for (int i = 0; i < 4; ++i)
#pragma unroll
        for (int j = 0; j < 4; ++j)
            acc[i][j] = (f32x4){0.f, 0.f, 0.f, 0.f};

    gemm_core<KD>(gA1, gA2, gB1, gB2, As, Bs, tid, wv, lane, acc);

    const int row15 = lane & 15, quad = lane >> 4;
    const int wm = (wv & 1) * 64, wn = (wv >> 1) * 64;
#pragma unroll
    for (int i = 0; i < 4; ++i) {
#pragma unroll
        for (int r = 0; r < 4; ++r) {
            int m = rowbase + wm + i * 16 + quad * 4 + r;
            int bb = m >> 10, l = m & 1023;
#pragma unroll
            for (int j = 0; j < 4; ++j) {
                int n = nbase + wn + j * 16 + row15;
                size_t off = (((size_t)(bb * 16 + (n >> 6)) * 1024) + l) * 64 + (n & 63);
                out[off] = acc[i][j][r];
            }
        }
    }
}

// ---------------------------------------------------------------------------
// Row-gathered GEMM over per-bank token lists (Q'/K'). grid.x = 66 row-tiles
// shared across 3 banks (sum ceil(cnt_p/128) <= 66); grid.y = 8 col-tiles.
// ---------------------------------------------------------------------------
template <int KD>
__global__ __launch_bounds__(256)
void gemm_prime(const float* __restrict__ A, const float* __restrict__ Wb,
                const int* __restrict__ cnt, const int* __restrict__ list,
                float* __restrict__ out)
{
    const int c0 = cnt[0], c1 = cnt[1], c2 = cnt[2];
    const int t0 = (c0 + 127) >> 7, t1 = (c1 + 127) >> 7, t2 = (c2 + 127) >> 7;
    const int rt = blockIdx.x;
    int bank, lt, cb;
    if (rt < t0)                { bank = 0; lt = rt;            cb = c0; }
    else if (rt < t0 + t1)      { bank = 1; lt = rt - t0;       cb = c1; }
    else if (rt < t0 + t1 + t2) { bank = 2; lt = rt - t0 - t1;  cb = c2; }
    else return;                       // uniform across block: no barrier reached

    const int* bl = list + bank * 8192;
    const float* W = Wb + (size_t)bank * 1024 * KD;

    __shared__ __align__(16) u16 As[128 * 32];
    __shared__ __align__(16) u16 Bs[128 * 32];
    const int tid  = threadIdx.x;
    const int lane = tid & 63;
    const int wv   = tid >> 6;
    const int nbase = blockIdx.y * 128;
    const int r1   = tid >> 2;
    const int koff = (tid & 3) * 8;

    int i1 = lt * 128 + r1;       if (i1 >= cb) i1 = cb - 1;
    int i2 = lt * 128 + 64 + r1;  if (i2 >= cb) i2 = cb - 1;
    const float* gA1 = A + (size_t)bl[i1] * KD + koff;
    const float* gA2 = A + (size_t)bl[i2] * KD + koff;
    const float* gB1 = W + (size_t)(nbase + r1) * KD + koff;
    const float* gB2 = W + (size_t)(nbase + 64 + r1) * KD + koff;

    f32x4 acc[4][4];
#pragma unroll
    for (int i = 0; i < 4; ++i)
#pragma unroll
        for (int j = 0; j < 4; ++j)
            acc[i][j] = (f32x4){0.f, 0.f, 0.f, 0.f};

    gemm_core<KD>(gA1, gA2, gB1, gB2, As, Bs, tid, wv, lane, acc);

    const int row15 = lane & 15, quad = lane >> 4;
    const int wm = (wv & 1) * 64, wn = (wv >> 1) * 64;
#pragma unroll
    for (int i = 0; i < 4; ++i) {
#pragma unroll
        for (int r = 0; r < 4; ++r) {
            int idx = lt * 128 + wm + i * 16 + quad * 4 + r;
            if (idx < cb) {
                int m = bl[idx];
                int bb = m >> 10, l = m & 1023;
#pragma unroll
                for (int j = 0; j < 4; ++j) {
                    int n = nbase + wn + j * 16 + row15;
                    size_t off = (((size_t)(bb * 16 + (n >> 6)) * 1024) + l) * 64 + (n & 63);
                    out[off] = acc[i][j][r];
                }
            }
        }
    }
}

// ---------------------------------------------------------------------------
extern "C" void kernel_launch(void* const* d_in, const int* in_sizes, int n_in,
                              void* d_out, int out_size, void* d_ws, size_t ws_size,
                              hipStream_t stream)
{
    const float* img = (const float*)d_in[0];
    const float* txt = (const float*)d_in[1];
    const float* Wq  = (const float*)d_in[2];
    const float* Wk  = (const float*)d_in[3];
    const float* Wv  = (const float*)d_in[4];
    const float* Wqb = (const float*)d_in[5];
    const float* Wkb = (const float*)d_in[6];
    const float* Wrq = (const float*)d_in[7];
    const float* Wrk = (const float*)d_in[8];
    float* out = (float*)d_out;

    int* cntq  = (int*)d_ws;                    // 3 ints
    int* cntk  = cntq + 3;                      // 3 ints
    int* qlist = (int*)((char*)d_ws + 32);      // 3*8192 ints
    int* klist = qlist + 3 * 8192;              // 3*8192 ints

    const size_t OSZ = (size_t)8 * 16 * 1024 * 64;   // 8,388,608 elements per output

    hipMemsetAsync(d_ws, 0, 32, stream);   // zero the 6 counters (ws is poisoned 0xAA)

    route_kernel<<<32, 256, 0, stream>>>(img, Wrq, 1024, 8192, cntq, qlist);
    route_kernel<<<32, 256, 0, stream>>>(txt, Wrk,  768, 8192, cntk, klist);

    gemm_heads<1024><<<dim3(64, 8), 256, 0, stream>>>(img, Wq, out);
    gemm_heads<768> <<<dim3(64, 8), 256, 0, stream>>>(txt, Wk, out + OSZ);
    gemm_heads<768> <<<dim3(64, 8), 256, 0, stream>>>(txt, Wv, out + 2 * OSZ);

    gemm_prime<1024><<<dim3(66, 8), 256, 0, stream>>>(img, Wqb, cntq, qlist, out + 3 * OSZ);
    gemm_prime<768> <<<dim3(66, 8), 256, 0, stream>>>(txt, Wkb, cntk, klist, out + 4 * OSZ);
}